// Round 1
// baseline (75.191 us; speedup 1.0000x reference)
//
#include <hip/hip_runtime.h>

// DownscaleLabel: label [8,1024,1024] int32 in [-1,6] -> out [8,1,64,64] int32.
// Per 16x16 block: histogram of (label & 7)  (maps -1 -> bin 7 == "ignore"),
// first-max argmax, output -1 if argmax==7 or max count < 192 (0.75*256).
// Wave-per-output-pixel: lane i int4-loads row (i>>2), 16B chunk (i&3).

#define B_ 8
#define H_ 1024
#define W_ 1024
#define TH_ 64
#define TW_ 64

__global__ __launch_bounds__(256) void downscale_label_kernel(
    const int* __restrict__ label, int* __restrict__ out) {
  const int lane = threadIdx.x & 63;
  const int wave = threadIdx.x >> 6;
  const int p = blockIdx.x * 4 + wave;          // output pixel id, 0..32767
  const int tw = p & (TW_ - 1);
  const int th = (p >> 6) & (TH_ - 1);
  const int b  = p >> 12;

  const int row = th * 16 + (lane >> 2);
  const int col = tw * 16 + ((lane & 3) << 2);
  const int4 v = *reinterpret_cast<const int4*>(
      label + ((size_t)(b * H_ + row) * W_ + col));

  // Pack per-lane histogram: 8 classes x 16 bits across two u64s.
  unsigned long long lo = 0ull, hi = 0ull;
  int vals[4] = {v.x, v.y, v.z, v.w};
#pragma unroll
  for (int j = 0; j < 4; ++j) {
    const int cls = vals[j] & 7;                // -1 -> 7, 0..6 unchanged
    const unsigned long long inc = 1ull << ((cls & 3) << 4);
    if (cls & 4) hi += inc; else lo += inc;     // compiles to cndmask adds
  }

  // Wave butterfly reduction (64 lanes).
#pragma unroll
  for (int s = 1; s < 64; s <<= 1) {
    lo += __shfl_xor(lo, s, 64);
    hi += __shfl_xor(hi, s, 64);
  }

  if (lane == 0) {
    int best = 0;
    int bc = (int)(lo & 0xFFFF);
#pragma unroll
    for (int c = 1; c < 8; ++c) {
      const unsigned long long src = (c < 4) ? lo : hi;
      const int cnt = (int)((src >> ((c & 3) << 4)) & 0xFFFF);
      if (cnt > bc) { bc = cnt; best = c; }     // strict > keeps first max
    }
    out[p] = (best == 7 || bc < 192) ? -1 : best;
  }
}

extern "C" void kernel_launch(void* const* d_in, const int* in_sizes, int n_in,
                              void* d_out, int out_size, void* d_ws, size_t ws_size,
                              hipStream_t stream) {
  const int* label = (const int*)d_in[0];
  int* out = (int*)d_out;
  const int n_pixels = B_ * TH_ * TW_;          // 32768
  const int blocks = n_pixels / 4;              // 4 waves per 256-thread block
  downscale_label_kernel<<<blocks, 256, 0, stream>>>(label, out);
}

// Round 2
// 70.301 us; speedup vs baseline: 1.0696x; 1.0696x over previous
//
#include <hip/hip_runtime.h>

// DownscaleLabel: label [8,1024,1024] int32 in [-1,6] -> out [8,1,64,64] int32.
// Per 16x16 block: histogram of (label & 7) (-1 -> bin 7), first-max argmax,
// -1 if argmax==7 or max count < 192 (0.75*256). All-integer, exact.
//
// Layout: 512 blocks = one per (b, th) strip of 16 rows x 1024 cols.
// Thread t (0..255) owns column chunk t (4 ints = 16B): wave reads 1024
// contiguous bytes per row (perfectly coalesced), 16 rows deep (16
// independent int4 loads/thread for MLP). Per-thread packed histogram
// (8 classes x 16-bit in two u64), then 2-step butterfly across the 4
// threads of each tw (counts <= 256 fit in 16 bits).

#define B_ 8
#define H_ 1024
#define W_ 1024
#define TH_ 64
#define TW_ 64

__global__ __launch_bounds__(256) void downscale_label_kernel(
    const int* __restrict__ label, int* __restrict__ out) {
  const int t = threadIdx.x;                 // column chunk 0..255
  const int bid = blockIdx.x;                // b*64 + th
  const int b = bid >> 6;
  const int th = bid & 63;

  const size_t base = ((size_t)(b * H_ + th * 16)) * W_ + (size_t)t * 4;
  const int4* p = reinterpret_cast<const int4*>(label + base);

  unsigned long long lo = 0ull, hi = 0ull;   // classes 0-3 / 4-7, 16b fields
#pragma unroll
  for (int r = 0; r < 16; ++r) {
    const int4 v = p[r * (W_ / 4)];          // byte stride 4096
    const int vals[4] = {v.x, v.y, v.z, v.w};
#pragma unroll
    for (int j = 0; j < 4; ++j) {
      const int cls = vals[j] & 7;           // -1 -> 7, 0..6 unchanged
      const unsigned long long inc = 1ull << ((cls & 3) << 4);
      if (cls & 4) hi += inc; else lo += inc;
    }
  }

  // Reduce across the 4 threads sharing one tw (lanes 4k..4k+3, same wave).
#pragma unroll
  for (int s = 1; s < 4; s <<= 1) {
    lo += __shfl_xor(lo, s, 64);
    hi += __shfl_xor(hi, s, 64);
  }

  if ((t & 3) == 0) {
    int best = 0;
    int bc = (int)(lo & 0xFFFF);
#pragma unroll
    for (int c = 1; c < 8; ++c) {
      const unsigned long long src = (c < 4) ? lo : hi;
      const int cnt = (int)((src >> ((c & 3) << 4)) & 0xFFFF);
      if (cnt > bc) { bc = cnt; best = c; }  // strict > keeps first max
    }
    out[bid * TW_ + (t >> 2)] = (best == 7 || bc < 192) ? -1 : best;
  }
}

extern "C" void kernel_launch(void* const* d_in, const int* in_sizes, int n_in,
                              void* d_out, int out_size, void* d_ws, size_t ws_size,
                              hipStream_t stream) {
  const int* label = (const int*)d_in[0];
  int* out = (int*)d_out;
  downscale_label_kernel<<<B_ * TH_, 256, 0, stream>>>(label, out);
}